// Round 2
// baseline (1316.635 us; speedup 1.0000x reference)
//
#include <hip/hip_runtime.h>

// Problem constants (B,H,L,D) = (2,16,2048,128), all fp32.
constexpr int Bc = 2, Hc = 16, Lc = 2048, Dc = 128;
constexpr int BHc = Bc * Hc;                        // 32
constexpr float RSCALE = 0.08838834764831845f;      // 1/sqrt(128)
constexpr size_t OUT_ELEMS = (size_t)BHc * Lc * Dc; // 8388608, start of attn_weight region
constexpr size_t SPLIT_ELEMS = (size_t)BHc * Lc * Dc;
constexpr size_t WS_NEED = SPLIT_ELEMS * 2 * 4;     // Kh,Kl,Vth,Vtl bf16 = 67MB

typedef float  f32x4 __attribute__((ext_vector_type(4)));
typedef short  s16x8 __attribute__((ext_vector_type(8)));

#define AS1(p) (const __attribute__((address_space(1))) void*)(p)
#define AS3(p) (__attribute__((address_space(3))) void*)(p)

// ---------------------------------------------------------------------------
// fp32 -> bf16 hi/lo split (RNE). hi+lo reproduces x to ~2^-17 relative.
// ---------------------------------------------------------------------------
__device__ __forceinline__ ushort bf16_rne(float x) {
    unsigned u = __float_as_uint(x);
    return (ushort)((u + 0x7FFFu + ((u >> 16) & 1u)) >> 16);
}
__device__ __forceinline__ void split1(float x, ushort& h, ushort& l) {
    ushort hb = bf16_rne(x);
    float hf = __uint_as_float((unsigned)hb << 16);
    h = hb;
    l = bf16_rne(x - hf);
}

// ---------------------------------------------------------------------------
// K0a: elementwise split of K into bf16 hi/lo arrays.
// ---------------------------------------------------------------------------
__global__ __launch_bounds__(256)
void k_split(const float* __restrict__ x, ushort* __restrict__ h, ushort* __restrict__ l)
{
    const int n4 = (int)(SPLIT_ELEMS / 4);
    const int stride = gridDim.x * blockDim.x;
    for (int i = blockIdx.x * blockDim.x + threadIdx.x; i < n4; i += stride) {
        float4 v = ((const float4*)x)[i];
        ushort4 hh, ll;
        split1(v.x, hh.x, ll.x); split1(v.y, hh.y, ll.y);
        split1(v.z, hh.z, ll.z); split1(v.w, hh.w, ll.w);
        ((ushort4*)h)[i] = hh;
        ((ushort4*)l)[i] = ll;
    }
}

// ---------------------------------------------------------------------------
// K0b: V (bh,L,D) -> Vt (bh,D,L) transposed + split to bf16 hi/lo.
// ---------------------------------------------------------------------------
__global__ __launch_bounds__(256)
void k_vsplit(const float* __restrict__ V, ushort* __restrict__ Vth, ushort* __restrict__ Vtl)
{
    __shared__ float Vs[64][132];
    const int kt = blockIdx.x, bh = blockIdx.y;
    const int k0 = kt * 64;
    const int tid = threadIdx.x;
    const float* Vb = V + ((size_t)bh * Lc + k0) * Dc;

#pragma unroll
    for (int i = 0; i < 8; i++) {
        int u = tid + 256 * i;          // 0..2047 float4 units
        int row = u >> 5, c4 = u & 31;  // 64 rows x 32 float4
        float4 v = *(const float4*)(Vb + (size_t)row * Dc + c4 * 4);
        *(float4*)&Vs[row][c4 * 4] = v;
    }
    __syncthreads();

    const int d = tid >> 1, part = tid & 1;  // d 0..127, 32 k each
    size_t off = ((size_t)bh * Dc + d) * Lc + k0 + part * 32;
#pragma unroll
    for (int j4 = 0; j4 < 8; j4++) {
        ushort4 hh, ll;
        split1(Vs[part * 32 + j4 * 4 + 0][d], hh.x, ll.x);
        split1(Vs[part * 32 + j4 * 4 + 1][d], hh.y, ll.y);
        split1(Vs[part * 32 + j4 * 4 + 2][d], hh.z, ll.z);
        split1(Vs[part * 32 + j4 * 4 + 3][d], hh.w, ll.w);
        *(ushort4*)(Vth + off + j4 * 4) = hh;
        *(ushort4*)(Vtl + off + j4 * 4) = ll;
    }
}

// ---------------------------------------------------------------------------
// K_FUSED: one block = 32 q-rows x full k (2048) for one bh.
// 512 threads = 8 waves. Full S strip lives in registers (acc[2][16] f32x4).
// Phase 1: QK^T split-bf16 MFMA, K double-buffered via pre-swizzled
//          global_load_lds + counted vmcnt + raw barriers.
// Phase 2: multiplier (A,D) applied in registers.
// Phase 3: exact softmax in registers (butterfly + cross-wave LDS reduce).
// Phase 4: write attn (only 537MB HBM touch) + PV via swizzled P-LDS tiles,
//          V^T B-frags straight from global.
// ---------------------------------------------------------------------------
__global__ __launch_bounds__(512, 2)
void k_fused(const float* __restrict__ Qg,
             const ushort* __restrict__ Kh, const ushort* __restrict__ Kl,
             const ushort* __restrict__ Vth, const ushort* __restrict__ Vtl,
             const float* __restrict__ Ag, const float* __restrict__ Dg,
             const float* __restrict__ wAg, const float* __restrict__ wDg,
             float* __restrict__ attn, float* __restrict__ Og)
{
    __shared__ ushort Qh_s[32 * 128], Ql_s[32 * 128];   // 8KB + 8KB (swizzled)
    __shared__ ushort Ks[2][2][128 * 128];              // [buf][hi/lo], 128KB
    __shared__ float  red[2][8][32];                    // 2KB
    ushort* Ph_s = &Ks[0][0][0];                        // P tile overlays Ks[0] (PV phase)
    ushort* Pl_s = &Ks[0][1][0];

    const int qt = blockIdx.x, bh = blockIdx.y;
    const int b = bh >> 4, h = bh & 15;
    const int q0 = qt * 32;
    const int tid = threadIdx.x;
    const int lane = tid & 63, wid = tid >> 6;
    const int l15 = lane & 15, g = lane >> 4;

    const ushort* Khb = Kh + (size_t)bh * Lc * Dc;
    const ushort* Klb = Kl + (size_t)bh * Lc * Dc;

    // ---- Phase 0: load Q strip fp32, split, swizzled ds_write -------------
    {
        int row = tid >> 4, s = tid & 15;   // 512 units: 32 rows x 16 segs(8 bf16)
        const float* src = Qg + ((size_t)bh * Lc + q0 + row) * Dc + s * 8;
        float4 a = *(const float4*)src;
        float4 c = *(const float4*)(src + 4);
        union { ushort us[8]; s16x8 v; } H, L;
        split1(a.x, H.us[0], L.us[0]); split1(a.y, H.us[1], L.us[1]);
        split1(a.z, H.us[2], L.us[2]); split1(a.w, H.us[3], L.us[3]);
        split1(c.x, H.us[4], L.us[4]); split1(c.y, H.us[5], L.us[5]);
        split1(c.z, H.us[6], L.us[6]); split1(c.w, H.us[7], L.us[7]);
        int p = s ^ (row & 7);
        *(s16x8*)&Qh_s[row * 128 + p * 8] = H.v;
        *(s16x8*)&Ql_s[row * 128 + p * 8] = L.v;
    }

    // Stage one 128x128 K tile (hi+lo) with pre-swizzled global source so the
    // linear LDS dest holds the XOR-swizzled layout (rule #21 both-sides).
#define STAGE(buf, t)                                                          \
    {                                                                          \
        _Pragma("unroll")                                                      \
        for (int i = 0; i < 4; i++) {                                          \
            int u = tid + 512 * i;                                             \
            int row = u >> 4, p = u & 15;                                      \
            int s = p ^ (row & 7);                                             \
            size_t goff = (size_t)((t) * 128 + row) * Dc + s * 8;              \
            __builtin_amdgcn_global_load_lds(AS1(Khb + goff),                  \
                AS3(&Ks[buf][0][u * 8]), 16, 0, 0);                            \
            __builtin_amdgcn_global_load_lds(AS1(Klb + goff),                  \
                AS3(&Ks[buf][1][u * 8]), 16, 0, 0);                            \
        }                                                                      \
    }

    f32x4 acc[2][16];
#pragma unroll
    for (int m = 0; m < 2; m++)
#pragma unroll
        for (int t = 0; t < 16; t++) acc[m][t] = (f32x4){0.f, 0.f, 0.f, 0.f};

    STAGE(0, 0);
    asm volatile("s_waitcnt lgkmcnt(0)" ::: "memory");  // Q ds_writes drained
    __builtin_amdgcn_s_barrier();

    // Q fragments -> registers once (reused for all 16 k-tiles): 64 VGPR.
    s16x8 QAh[2][4], QAl[2][4];
#pragma unroll
    for (int m = 0; m < 2; m++)
#pragma unroll
        for (int c = 0; c < 4; c++) {
            int qrow = m * 16 + l15;
            int sA = (c * 4 + g) ^ (qrow & 7);
            QAh[m][c] = *(const s16x8*)&Qh_s[qrow * 128 + sA * 8];
            QAl[m][c] = *(const s16x8*)&Ql_s[qrow * 128 + sA * 8];
        }

    // ---- Phase 1: QK^T over 16 k-tiles, double-buffered ------------------
#pragma unroll
    for (int t = 0; t < 16; t++) {
        if (t < 15) STAGE((t + 1) & 1, t + 1);
        if (t < 15) asm volatile("s_waitcnt vmcnt(8)" ::: "memory");
        else        asm volatile("s_waitcnt vmcnt(0)" ::: "memory");
        __builtin_amdgcn_s_barrier();
        __builtin_amdgcn_sched_barrier(0);

        const ushort* KH = &Ks[t & 1][0][0];
        const ushort* KL = &Ks[t & 1][1][0];
        const int krow = wid * 16 + l15;
        __builtin_amdgcn_s_setprio(1);
#pragma unroll
        for (int c = 0; c < 4; c++) {
            int sB = (c * 4 + g) ^ (krow & 7);
            s16x8 Bh = *(const s16x8*)&KH[krow * 128 + sB * 8];
            s16x8 Bl = *(const s16x8*)&KL[krow * 128 + sB * 8];
#pragma unroll
            for (int m = 0; m < 2; m++) {
                acc[m][t] = __builtin_amdgcn_mfma_f32_16x16x32_bf16(QAh[m][c], Bh, acc[m][t], 0, 0, 0);
                acc[m][t] = __builtin_amdgcn_mfma_f32_16x16x32_bf16(QAh[m][c], Bl, acc[m][t], 0, 0, 0);
                acc[m][t] = __builtin_amdgcn_mfma_f32_16x16x32_bf16(QAl[m][c], Bh, acc[m][t], 0, 0, 0);
            }
        }
        __builtin_amdgcn_s_setprio(0);
        __builtin_amdgcn_sched_barrier(0);
        __builtin_amdgcn_s_barrier();
    }

    // ---- Phase 2: multiplier (1 + A*wA + D*wD) * RSCALE ------------------
    const float wa = wAg[h], wd = wDg[h];
    const float* Ab = Ag + (size_t)b * Lc * Lc;
    const float* Db = Dg + (size_t)b * Lc * Lc;
#pragma unroll
    for (int t = 0; t < 16; t++) {
        int col = t * 128 + wid * 16 + l15;
#pragma unroll
        for (int m = 0; m < 2; m++)
#pragma unroll
            for (int r = 0; r < 4; r++) {
                int q = q0 + m * 16 + g * 4 + r;
                size_t off = (size_t)q * Lc + col;
                float mult = fmaf(Ab[off], wa, fmaf(Db[off], wd, 1.0f));
                acc[m][t][r] *= mult * RSCALE;
            }
    }

    // ---- Phase 3: exact softmax in registers -----------------------------
    float mrow[2][4];
#pragma unroll
    for (int m = 0; m < 2; m++)
#pragma unroll
        for (int r = 0; r < 4; r++) {
            float mv = acc[m][0][r];
#pragma unroll
            for (int t = 1; t < 16; t++) mv = fmaxf(mv, acc[m][t][r]);
#pragma unroll
            for (int mask = 1; mask < 16; mask <<= 1) mv = fmaxf(mv, __shfl_xor(mv, mask));
            mrow[m][r] = mv;
        }
    if (l15 == 0) {
#pragma unroll
        for (int m = 0; m < 2; m++)
#pragma unroll
            for (int r = 0; r < 4; r++) red[0][wid][m * 16 + g * 4 + r] = mrow[m][r];
    }
    __syncthreads();
#pragma unroll
    for (int m = 0; m < 2; m++)
#pragma unroll
        for (int r = 0; r < 4; r++) {
            int row = m * 16 + g * 4 + r;
            float mm = red[0][0][row];
#pragma unroll
            for (int w = 1; w < 8; w++) mm = fmaxf(mm, red[0][w][row]);
            mrow[m][r] = mm;
        }

    float lrow[2][4];
#pragma unroll
    for (int m = 0; m < 2; m++)
#pragma unroll
        for (int r = 0; r < 4; r++) {
            float sv = 0.f;
#pragma unroll
            for (int t = 0; t < 16; t++) {
                float e = __expf(acc[m][t][r] - mrow[m][r]);
                acc[m][t][r] = e;
                sv += e;
            }
#pragma unroll
            for (int mask = 1; mask < 16; mask <<= 1) sv += __shfl_xor(sv, mask);
            lrow[m][r] = sv;
        }
    if (l15 == 0) {
#pragma unroll
        for (int m = 0; m < 2; m++)
#pragma unroll
            for (int r = 0; r < 4; r++) red[1][wid][m * 16 + g * 4 + r] = lrow[m][r];
    }
    __syncthreads();
#pragma unroll
    for (int m = 0; m < 2; m++)
#pragma unroll
        for (int r = 0; r < 4; r++) {
            int row = m * 16 + g * 4 + r;
            float ss = red[1][0][row];
#pragma unroll
            for (int w = 1; w < 8; w++) ss += red[1][w][row];
            float rinv = 1.0f / ss;
#pragma unroll
            for (int t = 0; t < 16; t++) acc[m][t][r] *= rinv;
        }

    // ---- Phase 4: write attn + PV ----------------------------------------
    const ushort* Vhb = Vth + (size_t)bh * Dc * Lc;
    const ushort* Vlb = Vtl + (size_t)bh * Dc * Lc;
    float* attnb = attn + ((size_t)bh * Lc + q0) * Lc;

    f32x4 oacc[2];
    oacc[0] = (f32x4){0.f, 0.f, 0.f, 0.f};
    oacc[1] = (f32x4){0.f, 0.f, 0.f, 0.f};

    __syncthreads();   // all K-tile reads done; safe to overlay P onto Ks[0]

#pragma unroll
    for (int t = 0; t < 16; t++) {
        const int kk = wid * 16 + l15;
#pragma unroll
        for (int m = 0; m < 2; m++)
#pragma unroll
            for (int r = 0; r < 4; r++) {
                int q = m * 16 + g * 4 + r;
                float p = acc[m][t][r];
                attnb[(size_t)q * Lc + t * 128 + kk] = p;
                ushort hu, lu;
                split1(p, hu, lu);
                int seg = (kk >> 3) ^ (q & 7);
                Ph_s[q * 128 + seg * 8 + (kk & 7)] = hu;
                Pl_s[q * 128 + seg * 8 + (kk & 7)] = lu;
            }
        __syncthreads();

        __builtin_amdgcn_s_setprio(1);
#pragma unroll
        for (int kc = 0; kc < 4; kc++) {
            const int dd = wid * 16 + l15;
            size_t voff = (size_t)dd * Lc + t * 128 + kc * 32 + g * 8;
            s16x8 Bh = *(const s16x8*)(Vhb + voff);
            s16x8 Bl = *(const s16x8*)(Vlb + voff);
#pragma unroll
            for (int m = 0; m < 2; m++) {
                int qrow = m * 16 + l15;
                int sP = (kc * 4 + g) ^ (qrow & 7);
                s16x8 Ph = *(const s16x8*)&Ph_s[qrow * 128 + sP * 8];
                s16x8 Pl = *(const s16x8*)&Pl_s[qrow * 128 + sP * 8];
                oacc[m] = __builtin_amdgcn_mfma_f32_16x16x32_bf16(Ph, Bh, oacc[m], 0, 0, 0);
                oacc[m] = __builtin_amdgcn_mfma_f32_16x16x32_bf16(Ph, Bl, oacc[m], 0, 0, 0);
                oacc[m] = __builtin_amdgcn_mfma_f32_16x16x32_bf16(Pl, Bh, oacc[m], 0, 0, 0);
            }
        }
        __builtin_amdgcn_s_setprio(0);
        __syncthreads();
    }

#pragma unroll
    for (int m = 0; m < 2; m++)
#pragma unroll
        for (int r = 0; r < 4; r++) {
            int q = q0 + m * 16 + g * 4 + r;
            Og[((size_t)bh * Lc + q) * Dc + wid * 16 + l15] = oacc[m][r];
        }
#undef STAGE
}

// ---------------------------------------------------------------------------
// Fallback fp32 path (verified) if workspace is too small.
// ---------------------------------------------------------------------------
__global__ __launch_bounds__(256)
void k_scores(const float* __restrict__ Qg, const float* __restrict__ Kg,
              const float* __restrict__ Ag, const float* __restrict__ Dg,
              const float* __restrict__ wAg, const float* __restrict__ wDg,
              float* __restrict__ Sg)
{
    __shared__ float Qs[128][36];
    __shared__ float Ks2[128][36];

    const int kt = blockIdx.x, qt = blockIdx.y, bh = blockIdx.z;
    const int b = bh >> 4, h = bh & 15;
    const int q0 = qt * 128, k0 = kt * 128;
    const int tid = threadIdx.x;
    const int tx = tid & 15, ty = tid >> 4;

    const float wa = wAg[h], wd = wDg[h];
    const float* Qb = Qg + ((size_t)bh * Lc + q0) * Dc;
    const float* Kb = Kg + ((size_t)bh * Lc + k0) * Dc;

    float acc[8][8];
#pragma unroll
    for (int i = 0; i < 8; i++)
#pragma unroll
        for (int j = 0; j < 8; j++) acc[i][j] = 0.0f;

    for (int c = 0; c < 4; c++) {
#pragma unroll
        for (int i = 0; i < 4; i++) {
            int idx = tid + 256 * i;
            int row = idx >> 3;
            int c4  = idx & 7;
            float4 qv = *(const float4*)(Qb + (size_t)row * Dc + c * 32 + c4 * 4);
            float4 kv = *(const float4*)(Kb + (size_t)row * Dc + c * 32 + c4 * 4);
            *(float4*)&Qs[row][c4 * 4] = qv;
            *(float4*)&Ks2[row][c4 * 4] = kv;
        }
        __syncthreads();

#pragma unroll
        for (int d4 = 0; d4 < 8; d4++) {
            float4 a[8], bbv[8];
#pragma unroll
            for (int i = 0; i < 8; i++) a[i]   = *(const float4*)&Qs[ty + 16 * i][d4 * 4];
#pragma unroll
            for (int j = 0; j < 8; j++) bbv[j] = *(const float4*)&Ks2[tx + 16 * j][d4 * 4];
#pragma unroll
            for (int i = 0; i < 8; i++)
#pragma unroll
                for (int j = 0; j < 8; j++)
                    acc[i][j] += a[i].x * bbv[j].x + a[i].y * bbv[j].y
                               + a[i].z * bbv[j].z + a[i].w * bbv[j].w;
        }
        __syncthreads();
    }

    const float* Arow = Ag + (size_t)b * Lc * Lc;
    const float* Drow = Dg + (size_t)b * Lc * Lc;
    float* Srow = Sg + (size_t)bh * Lc * Lc;
#pragma unroll
    for (int i = 0; i < 8; i++) {
        int q = q0 + ty + 16 * i;
        size_t ro = (size_t)q * Lc + k0;
#pragma unroll
        for (int j = 0; j < 8; j++) {
            int k = tx + 16 * j;
            float av = Arow[ro + k];
            float dv = Drow[ro + k];
            float mult = 1.0f + av * wa + dv * wd;
            Srow[ro + k] = acc[i][j] * mult * RSCALE;
        }
    }
}

__global__ __launch_bounds__(256)
void k_softmax(float* __restrict__ Sg)
{
    __shared__ float red[8];
    const size_t row = blockIdx.x;
    float* Sr = Sg + row * (size_t)Lc;
    const int tid = threadIdx.x;
    const int w = tid >> 6;

    float4 v0 = *(const float4*)(Sr + tid * 4);
    float4 v1 = *(const float4*)(Sr + 1024 + tid * 4);

    float m = fmaxf(fmaxf(fmaxf(v0.x, v0.y), fmaxf(v0.z, v0.w)),
                    fmaxf(fmaxf(v1.x, v1.y), fmaxf(v1.z, v1.w)));
#pragma unroll
    for (int off = 32; off; off >>= 1) m = fmaxf(m, __shfl_xor(m, off));
    if ((tid & 63) == 0) red[w] = m;
    __syncthreads();
    m = fmaxf(fmaxf(red[0], red[1]), fmaxf(red[2], red[3]));

    float4 e0, e1;
    e0.x = __expf(v0.x - m); e0.y = __expf(v0.y - m);
    e0.z = __expf(v0.z - m); e0.w = __expf(v0.w - m);
    e1.x = __expf(v1.x - m); e1.y = __expf(v1.y - m);
    e1.z = __expf(v1.z - m); e1.w = __expf(v1.w - m);

    float s = e0.x + e0.y + e0.z + e0.w + e1.x + e1.y + e1.z + e1.w;
#pragma unroll
    for (int off = 32; off; off >>= 1) s += __shfl_xor(s, off);
    if ((tid & 63) == 0) red[4 + w] = s;
    __syncthreads();
    float l = red[4] + red[5] + red[6] + red[7];
    float rinv = 1.0f / l;

    e0.x *= rinv; e0.y *= rinv; e0.z *= rinv; e0.w *= rinv;
    e1.x *= rinv; e1.y *= rinv; e1.z *= rinv; e1.w *= rinv;
    *(float4*)(Sr + tid * 4) = e0;
    *(float4*)(Sr + 1024 + tid * 4) = e1;
}

__global__ __launch_bounds__(256)
void k_pv(const float* __restrict__ Pg, const float* __restrict__ Vg,
          float* __restrict__ Og)
{
    __shared__ float Ps[128][36];
    __shared__ float Vs[32][132];

    const int qt = blockIdx.x, bh = blockIdx.y;
    const int q0 = qt * 128;
    const int tid = threadIdx.x;
    const int tx = tid & 15, ty = tid >> 4;

    const float* Pb = Pg + ((size_t)bh * Lc + q0) * (size_t)Lc;
    const float* Vb = Vg + (size_t)bh * Lc * Dc;

    float acc[8][8];
#pragma unroll
    for (int i = 0; i < 8; i++)
#pragma unroll
        for (int j = 0; j < 8; j++) acc[i][j] = 0.0f;

    for (int k0 = 0; k0 < Lc; k0 += 32) {
#pragma unroll
        for (int i = 0; i < 4; i++) {
            int idx = tid + 256 * i;
            int rowp = idx >> 3, c4p = idx & 7;
            *(float4*)&Ps[rowp][c4p * 4] =
                *(const float4*)(Pb + (size_t)rowp * Lc + k0 + c4p * 4);
            int rowv = idx >> 5, c4v = idx & 31;
            *(float4*)&Vs[rowv][c4v * 4] =
                *(const float4*)(Vb + (size_t)(k0 + rowv) * Dc + c4v * 4);
        }
        __syncthreads();

#pragma unroll
        for (int kk4 = 0; kk4 < 8; kk4++) {
            float4 a[8];
#pragma unroll
            for (int i = 0; i < 8; i++) a[i] = *(const float4*)&Ps[ty + 16 * i][kk4 * 4];
#pragma unroll
            for (int cc = 0; cc < 4; cc++) {
                int kk = kk4 * 4 + cc;
                float4 b0 = *(const float4*)&Vs[kk][tx * 4];
                float4 b1 = *(const float4*)&Vs[kk][64 + tx * 4];
#pragma unroll
                for (int i = 0; i < 8; i++) {
                    float av = (cc == 0) ? a[i].x : (cc == 1) ? a[i].y
                             : (cc == 2) ? a[i].z : a[i].w;
                    acc[i][0] += av * b0.x; acc[i][1] += av * b0.y;
                    acc[i][2] += av * b0.z; acc[i][3] += av * b0.w;
                    acc[i][4] += av * b1.x; acc[i][5] += av * b1.y;
                    acc[i][6] += av * b1.z; acc[i][7] += av * b1.w;
                }
            }
        }
        __syncthreads();
    }

#pragma unroll
    for (int i = 0; i < 8; i++) {
        int q = q0 + ty + 16 * i;
        float* Or = Og + ((size_t)bh * Lc + q) * Dc;
        *(float4*)(Or + tx * 4)      = make_float4(acc[i][0], acc[i][1], acc[i][2], acc[i][3]);
        *(float4*)(Or + 64 + tx * 4) = make_float4(acc[i][4], acc[i][5], acc[i][6], acc[i][7]);
    }
}

// ---------------------------------------------------------------------------
extern "C" void kernel_launch(void* const* d_in, const int* in_sizes, int n_in,
                              void* d_out, int out_size, void* d_ws, size_t ws_size,
                              hipStream_t stream)
{
    const float* Q  = (const float*)d_in[0];
    const float* K  = (const float*)d_in[1];
    const float* V  = (const float*)d_in[2];
    const float* A  = (const float*)d_in[3];
    const float* Ds = (const float*)d_in[4];
    const float* wA = (const float*)d_in[5];
    const float* wD = (const float*)d_in[6];

    float* out  = (float*)d_out;            // (B,H,L,D)
    float* attn = out + OUT_ELEMS;          // (B,H,L,L)

    if (d_ws != nullptr && ws_size >= WS_NEED) {
        ushort* Kh  = (ushort*)d_ws;
        ushort* Kl  = Kh  + SPLIT_ELEMS;
        ushort* Vth = Kl  + SPLIT_ELEMS;
        ushort* Vtl = Vth + SPLIT_ELEMS;

        hipLaunchKernelGGL(k_split, dim3(1024), dim3(256), 0, stream, K, Kh, Kl);
        hipLaunchKernelGGL(k_vsplit, dim3(Lc / 64, BHc), dim3(256), 0, stream, V, Vth, Vtl);
        hipLaunchKernelGGL(k_fused, dim3(Lc / 32, BHc), dim3(512), 0, stream,
                           Q, Kh, Kl, Vth, Vtl, A, Ds, wA, wD, attn, out);
    } else {
        hipLaunchKernelGGL(k_scores, dim3(Lc / 128, Lc / 128, BHc), dim3(256), 0, stream,
                           Q, K, A, Ds, wA, wD, attn);
        hipLaunchKernelGGL(k_softmax, dim3(BHc * Lc), dim3(256), 0, stream, attn);
        hipLaunchKernelGGL(k_pv, dim3(Lc / 128, BHc), dim3(256), 0, stream, attn, V, out);
    }
}